// Round 9
// baseline (128.696 us; speedup 1.0000x reference)
//
#include <hip/hip_runtime.h>
#include <hip/hip_fp16.h>
#include <math.h>

#define BB 4
#define CC 64
#define HH 128
#define WW 128
#define OO 64
#define HWW (HH * WW)

typedef _Float16 f16x8 __attribute__((ext_vector_type(8)));
typedef float f32x4 __attribute__((ext_vector_type(4)));

// ws byte offsets (weight fragments only, ~216 KB)
#define WHF_OFF  0          // main W hi frags: 18*4*64*8 halfs = 73728 B
#define WLF_OFF  73728      // main W lo frags
#define WOMH_OFF 147456     // om W hi frags: 18*2*64*8 halfs = 36864 B
#define WOML_OFF 184320     // om W lo frags

__device__ inline __half2 u2h(unsigned u) {
    union { unsigned u; __half2 h; } c; c.u = u; return c.h;
}
__device__ inline unsigned h2u(__half2 h) {
    union { __half2 h; unsigned u; } c; c.h = h; return c.u;
}

// ---------------------------------------------------------------------------
// prep: weights -> f16 hi/lo A-fragments (RNE split).
// chunk ch = half*9 + tap covers channels [half*32, half*32+32) of tap.
// A-frag: lane l holds W[o = grp*16 + (l&15)][k = (l>>4)*8 + j].
__global__ void prep_kernel(const float* __restrict__ weight,     // (O,C,3,3)
                            const float* __restrict__ om_weight,  // (27,C,3,3)
                            unsigned short* __restrict__ whf,
                            unsigned short* __restrict__ wlf,
                            unsigned short* __restrict__ womh,
                            unsigned short* __restrict__ woml)
{
    int d = blockIdx.x * 256 + threadIdx.x;
    if (d < 18 * 4 * 64 * 8) {
        int j  = d & 7;
        int l  = (d >> 3) & 63;
        int wv = (d >> 9) & 3;
        int ch = d >> 11;
        int o  = wv * 16 + (l & 15);
        int kk = (l >> 4) * 8 + j;
        int c  = (ch / 9) * 32 + kk;
        int tap = ch % 9;
        float w = weight[(o * CC + c) * 9 + tap];
        __half h = __float2half_rn(w);
        __half lo = __float2half_rn(w - __half2float(h));
        whf[d] = __half_as_ushort(h);
        wlf[d] = __half_as_ushort(lo);
    }
    int d2 = d - 18 * 4 * 64 * 8;
    if (d2 >= 0 && d2 < 18 * 2 * 64 * 8) {
        int j  = d2 & 7;
        int l  = (d2 >> 3) & 63;
        int og = (d2 >> 9) & 1;
        int ch = d2 >> 10;
        int o  = og * 16 + (l & 15);
        int kk = (l >> 4) * 8 + j;
        int c  = (ch / 9) * 32 + kk;
        int tap = ch % 9;
        float w = (o < 27) ? om_weight[(o * CC + c) * 9 + tap] : 0.f;
        __half h = __float2half_rn(w);
        __half lo = __float2half_rn(w - __half2float(h));
        womh[d2] = __half_as_ushort(h);
        woml[d2] = __half_as_ushort(lo);
    }
}

// ---------------------------------------------------------------------------
// Fused kernel: 32-pixel tiles, 256 threads = 4 waves, 4 blocks/CU.
// Full 64-channel x window staged ONCE as packed f16x2 (5x36 pos, zero halo).
// om conv: B-frags read directly from window (f16), no conversion math.
// main conv: packed-f16 bilinear (__hfma2), result = exchange payload.
__global__ void __launch_bounds__(256, 4)
fused_kernel(const float* __restrict__ x,     // (B,C,H,W)
             const unsigned short* __restrict__ whf,
             const unsigned short* __restrict__ wlf,
             const unsigned short* __restrict__ womh,
             const unsigned short* __restrict__ woml,
             const float* __restrict__ bias,
             const float* __restrict__ om_bias,
             float* __restrict__ out)         // (B,O,H,W)
{
    __shared__ __align__(16) uint2 Xf[16 * 180];       // [cg][pos] f16x2-pairs 23,040 B
    __shared__ __align__(16) unsigned vhf[2][32][21];  // frag exchange 5,376 B
    __shared__ __align__(16) uint4 swth4[288];         // packed f16x2 weights 4,608 B
    __shared__ int sidx[288];                          // 1,152 B  -> 34,176 B total

    int t    = threadIdx.x;
    int lane = t & 63;
    int wv   = t >> 6;

    int bid = blockIdx.x;           // b*512 + ho*4 + q
    int b   = bid >> 9;
    int r   = bid & 511;
    int ho  = r >> 2;
    int w0  = (r & 3) << 5;

    // ---------------- stage: all 64 ch -> LDS packed f16 (zero halo) -------
    {
        const float* xb = x + (size_t)b * CC * HWW;
#pragma unroll 1
        for (int i = t; i < 16 * 180; i += 256) {
            int cg  = i / 180;
            int pos = i - cg * 180;
            int rr  = pos / 36;
            int cc2 = pos - rr * 36;
            int gy = ho - 2 + rr, gx = w0 - 2 + cc2;
            bool ok = (gy >= 0) & (gy < HH) & (gx >= 0) & (gx < WW);
            int gi = ok ? gy * WW + gx : 0;
            const float* xc = xb + (size_t)cg * 4 * HWW + gi;
            float v0 = xc[0], v1 = xc[HWW], v2 = xc[2 * HWW], v3 = xc[3 * HWW];
            if (!ok) { v0 = 0.f; v1 = 0.f; v2 = 0.f; v3 = 0.f; }
            uint2 p;
            p.x = h2u(__floats2half2_rn(v0, v1));
            p.y = h2u(__floats2half2_rn(v2, v3));
            Xf[cg * 180 + pos] = p;
        }
    }
    __syncthreads();

    // ---------------- om conv: B direct from window, 2 MFMAs/tap -----------
    f32x4 accom = (f32x4){0.f, 0.f, 0.f, 0.f};
    {
        int og = wv & 1;
        int s  = wv >> 1;
        int pix_s = s * 16 + (lane & 15);
#pragma unroll 1
        for (int ch = 0; ch < 18; ch++) {
            int half = ch / 9;
            int tap  = ch - half * 9;
            int cg0  = half * 8 + (lane >> 4) * 2;
            int ky = tap / 3, kx = tap - ky * 3;
            int pos = (ky + 1) * 36 + pix_s + kx + 1;
            uint2 pa = Xf[cg0 * 180 + pos];
            uint2 pb = Xf[(cg0 + 1) * 180 + pos];
            union { f16x8 v; unsigned u[4]; } B;
            B.u[0] = pa.x; B.u[1] = pa.y; B.u[2] = pb.x; B.u[3] = pb.y;
            const f16x8 ah = *(const f16x8*)&womh[((size_t)(ch * 2 + og) * 64 + lane) * 8];
            const f16x8 al = *(const f16x8*)&woml[((size_t)(ch * 2 + og) * 64 + lane) * 8];
            accom = __builtin_amdgcn_mfma_f32_16x16x32_f16(ah, B.v, accom, 0, 0, 0);
            accom = __builtin_amdgcn_mfma_f32_16x16x32_f16(al, B.v, accom, 0, 0, 0);
        }
    }

    // om epilogue -> omL (union with vhf region; unused until main loop)
    float* omL = (float*)&vhf[0][0][0];   // 27*32 floats = 3,456 B < 5,376 B
    {
        int og = wv & 1, s = wv >> 1;
#pragma unroll
        for (int rg = 0; rg < 4; rg++) {
            int m = og * 16 + (lane >> 4) * 4 + rg;
            if (m < 27) {
                int pp = s * 16 + (lane & 15);
                float v = accom[rg] + om_bias[m];
                if (m >= 18) v = 1.f / (1.f + expf(-v));
                omL[m * 32 + pp] = v;
            }
        }
    }
    __syncthreads();

    // phase B: sampling params per (tap, pixel) -> packed f16x2 weights
#pragma unroll 1
    for (int it = t; it < 288; it += 256) {
        int k  = it >> 5;
        int pp = it & 31;
        float oy = omL[k * 32 + pp];
        float ox = omL[(9 + k) * 32 + pp];
        float mm = omL[(18 + k) * 32 + pp];
        int ky = k / 3, kx = k - ky * 3;
        float py = oy + (float)(ho + ky - 1);
        float px = ox + (float)(w0 + pp + kx - 1);
        float fy = floorf(py), fx = floorf(px);
        float ly = py - fy, lx = px - fx;
        int y0 = (int)fy, x0 = (int)fx;
        bool vy0 = (y0 >= 0) & (y0 < HH);
        bool vy1 = (y0 + 1 >= 0) & (y0 + 1 < HH);
        bool vx0 = (x0 >= 0) & (x0 < WW);
        bool vx1 = (x0 + 1 >= 0) & (x0 + 1 < WW);
        float w00 = (vy0 & vx0) ? (1.f - ly) * (1.f - lx) * mm : 0.f;
        float w01 = (vy0 & vx1) ? (1.f - ly) * lx * mm : 0.f;
        float w10 = (vy1 & vx0) ? ly * (1.f - lx) * mm : 0.f;
        float w11 = (vy1 & vx1) ? ly * lx * mm : 0.f;
        uint4 wp;
        wp.x = h2u(__float2half2_rn(w00));
        wp.y = h2u(__float2half2_rn(w01));
        wp.z = h2u(__float2half2_rn(w10));
        wp.w = h2u(__float2half2_rn(w11));
        swth4[it] = wp;
        bool inw = (y0 >= ho - 2) & (y0 <= ho + 1) & (x0 >= w0 - 2) & (x0 <= w0 + 32);
        int y0c = min(max(y0, -8), 135);
        int x0c = min(max(x0, -8), 135);
        sidx[it] = ((y0c + 16) << 16) | ((x0c + 16) & 0xFFFF)
                 | (inw ? 0 : (int)0x80000000);
    }
    __syncthreads();

    // ---------------- main conv: packed-f16 bilinear + exchange + MFMA -----
    f32x4 acc[2];
    acc[0] = (f32x4){0.f, 0.f, 0.f, 0.f};
    acc[1] = (f32x4){0.f, 0.f, 0.f, 0.f};

    {
        int pix = t & 31;
        int cg  = t >> 5;               // 0..7, 4 channels each (within half)
#pragma unroll 1
        for (int ach = 0; ach < 18; ach++) {
            int half = ach / 9;
            int tap  = ach - half * 9;
            int buf  = ach & 1;
            int cgg  = half * 8 + cg;
            const uint2* Xrow = &Xf[cgg * 180];
            int item = tap * 32 + pix;
            uint4 wp = swth4[item];
            int sv = sidx[item];
            int y0 = ((sv >> 16) & 0x7FFF) - 16;
            int x0 = (sv & 0xFFFF) - 16;
            const f16x8 ah = *(const f16x8*)&whf[((size_t)(ach * 4 + wv) * 64 + lane) * 8];
            const f16x8 al = *(const f16x8*)&wlf[((size_t)(ach * 4 + wv) * 64 + lane) * 8];

            uint2 hw;
            if (sv >= 0) {
                int o00 = (y0 - ho + 2) * 36 + (x0 - w0 + 2);
                uint2 c00 = Xrow[o00];
                uint2 c01 = Xrow[o00 + 1];
                uint2 c10 = Xrow[o00 + 36];
                uint2 c11 = Xrow[o00 + 37];
                __half2 w00 = u2h(wp.x), w01 = u2h(wp.y);
                __half2 w10 = u2h(wp.z), w11 = u2h(wp.w);
                __half2 vA = __hmul2(w00, u2h(c00.x));
                vA = __hfma2(w01, u2h(c01.x), vA);
                vA = __hfma2(w10, u2h(c10.x), vA);
                vA = __hfma2(w11, u2h(c11.x), vA);
                __half2 vB = __hmul2(w00, u2h(c00.y));
                vB = __hfma2(w01, u2h(c01.y), vB);
                vB = __hfma2(w10, u2h(c10.y), vB);
                vB = __hfma2(w11, u2h(c11.y), vB);
                hw.x = h2u(vA);
                hw.y = h2u(vB);
            } else {
                // rare escape: clamped global gather in f32
                const float* xg = x + ((size_t)(b * CC + half * 32 + cg * 4)) * HWW;
                float w00f = __low2float(u2h(wp.x)), w01f = __low2float(u2h(wp.y));
                float w10f = __low2float(u2h(wp.z)), w11f = __low2float(u2h(wp.w));
                int cy0 = min(max(y0, 0), HH - 1), cy1 = min(max(y0 + 1, 0), HH - 1);
                int cx0 = min(max(x0, 0), WW - 1), cx1 = min(max(x0 + 1, 0), WW - 1);
                int i00 = cy0 * WW + cx0, i01 = cy0 * WW + cx1;
                int i10 = cy1 * WW + cx0, i11 = cy1 * WW + cx1;
                float v0 = w00f * xg[i00] + w01f * xg[i01] + w10f * xg[i10] + w11f * xg[i11];
                const float* x1p = xg + HWW;
                float v1 = w00f * x1p[i00] + w01f * x1p[i01] + w10f * x1p[i10] + w11f * x1p[i11];
                const float* x2p = xg + 2 * HWW;
                float v2 = w00f * x2p[i00] + w01f * x2p[i01] + w10f * x2p[i10] + w11f * x2p[i11];
                const float* x3p = xg + 3 * HWW;
                float v3 = w00f * x3p[i00] + w01f * x3p[i01] + w10f * x3p[i10] + w11f * x3p[i11];
                hw.x = h2u(__floats2half2_rn(v0, v1));
                hw.y = h2u(__floats2half2_rn(v2, v3));
            }
            *(uint2*)&vhf[buf][pix][cg * 2] = hw;
            __syncthreads();
#pragma unroll
            for (int s2 = 0; s2 < 2; s2++) {
                union { f16x8 v; unsigned u[4]; } B;
                const unsigned* src = &vhf[buf][s2 * 16 + (lane & 15)][(lane >> 4) * 4];
                B.u[0] = src[0]; B.u[1] = src[1]; B.u[2] = src[2]; B.u[3] = src[3];
                acc[s2] = __builtin_amdgcn_mfma_f32_16x16x32_f16(ah, B.v, acc[s2], 0, 0, 0);
                acc[s2] = __builtin_amdgcn_mfma_f32_16x16x32_f16(al, B.v, acc[s2], 0, 0, 0);
            }
        }
    }

    // epilogue
    int prow = ho * WW + w0;
#pragma unroll
    for (int s = 0; s < 2; s++) {
#pragma unroll
        for (int rg = 0; rg < 4; rg++) {
            int o  = wv * 16 + (lane >> 4) * 4 + rg;
            int pp = s * 16 + (lane & 15);
            out[((size_t)(b * OO + o)) * HWW + prow + pp] = acc[s][rg] + bias[o];
        }
    }
}

// ---------------------------------------------------------------------------
extern "C" void kernel_launch(void* const* d_in, const int* in_sizes, int n_in,
                              void* d_out, int out_size, void* d_ws, size_t ws_size,
                              hipStream_t stream)
{
    (void)in_sizes; (void)n_in; (void)out_size; (void)ws_size;
    const float* x      = (const float*)d_in[0];
    const float* weight = (const float*)d_in[1];
    const float* bias   = (const float*)d_in[2];
    const float* om_w   = (const float*)d_in[3];
    const float* om_b   = (const float*)d_in[4];
    float* out = (float*)d_out;
    char*  ws  = (char*)d_ws;

    unsigned short* whf  = (unsigned short*)(ws + WHF_OFF);
    unsigned short* wlf  = (unsigned short*)(ws + WLF_OFF);
    unsigned short* womh = (unsigned short*)(ws + WOMH_OFF);
    unsigned short* woml = (unsigned short*)(ws + WOML_OFF);

    int prep_n = 18 * 4 * 64 * 8 + 18 * 2 * 64 * 8;  // 55296
    prep_kernel<<<(prep_n + 255) / 256, 256, 0, stream>>>(weight, om_w, whf, wlf, womh, woml);

    int nblk = BB * HH * (WW / 32);  // 2048
    fused_kernel<<<nblk, 256, 0, stream>>>(x, whf, wlf, womh, woml, bias, om_b, out);
}

// Round 10
// 119.802 us; speedup vs baseline: 1.0742x; 1.0742x over previous
//
#include <hip/hip_runtime.h>
#include <hip/hip_fp16.h>
#include <math.h>

#define BB 4
#define CC 64
#define HH 128
#define WW 128
#define OO 64
#define HWW (HH * WW)

typedef _Float16 f16x8 __attribute__((ext_vector_type(8)));
typedef float f32x4 __attribute__((ext_vector_type(4)));

// ws byte offsets (weight fragments only, ~216 KB)
#define WHF_OFF  0          // main W hi frags: 18*4*64*8 halfs = 73728 B
#define WLF_OFF  73728      // main W lo frags
#define WOMH_OFF 147456     // om W hi frags: 18*2*64*8 halfs = 36864 B
#define WOML_OFF 184320     // om W lo frags

__device__ inline __half2 u2h(unsigned u) {
    union { unsigned u; __half2 h; } c; c.u = u; return c.h;
}
__device__ inline unsigned h2u(__half2 h) {
    union { __half2 h; unsigned u; } c; c.h = h; return c.u;
}

// ---------------------------------------------------------------------------
// prep: weights -> f16 hi/lo A-fragments (RNE split).
// chunk ch = half*9 + tap covers channels [half*32, half*32+32) of tap.
// A-frag: lane l holds W[o = grp*16 + (l&15)][k = (l>>4)*8 + j].
__global__ void prep_kernel(const float* __restrict__ weight,     // (O,C,3,3)
                            const float* __restrict__ om_weight,  // (27,C,3,3)
                            unsigned short* __restrict__ whf,
                            unsigned short* __restrict__ wlf,
                            unsigned short* __restrict__ womh,
                            unsigned short* __restrict__ woml)
{
    int d = blockIdx.x * 256 + threadIdx.x;
    if (d < 18 * 4 * 64 * 8) {
        int j  = d & 7;
        int l  = (d >> 3) & 63;
        int wv = (d >> 9) & 3;
        int ch = d >> 11;
        int o  = wv * 16 + (l & 15);
        int kk = (l >> 4) * 8 + j;
        int c  = (ch / 9) * 32 + kk;
        int tap = ch % 9;
        float w = weight[(o * CC + c) * 9 + tap];
        __half h = __float2half_rn(w);
        __half lo = __float2half_rn(w - __half2float(h));
        whf[d] = __half_as_ushort(h);
        wlf[d] = __half_as_ushort(lo);
    }
    int d2 = d - 18 * 4 * 64 * 8;
    if (d2 >= 0 && d2 < 18 * 2 * 64 * 8) {
        int j  = d2 & 7;
        int l  = (d2 >> 3) & 63;
        int og = (d2 >> 9) & 1;
        int ch = d2 >> 10;
        int o  = og * 16 + (l & 15);
        int kk = (l >> 4) * 8 + j;
        int c  = (ch / 9) * 32 + kk;
        int tap = ch % 9;
        float w = (o < 27) ? om_weight[(o * CC + c) * 9 + tap] : 0.f;
        __half h = __float2half_rn(w);
        __half lo = __float2half_rn(w - __half2float(h));
        womh[d2] = __half_as_ushort(h);
        woml[d2] = __half_as_ushort(lo);
    }
}

// ---------------------------------------------------------------------------
// Fused kernel: 32-pixel tiles, 256 threads = 4 waves, 4 blocks/CU.
// Window [cg8][pos] uint4 (8 packed-f16 channels per entry): om B-frag and
// bilinear corners are single ds_read_b128. Whole-tap exchange: 9 barriers,
// 8 MFMAs per barrier.
__global__ void __launch_bounds__(256, 4)
fused_kernel(const float* __restrict__ x,     // (B,C,H,W)
             const unsigned short* __restrict__ whf,
             const unsigned short* __restrict__ wlf,
             const unsigned short* __restrict__ womh,
             const unsigned short* __restrict__ woml,
             const float* __restrict__ bias,
             const float* __restrict__ om_bias,
             float* __restrict__ out)         // (B,O,H,W)
{
    __shared__ __align__(16) uint4 Xw[8 * 180];    // [cg8][pos] 23,040 B
    __shared__ __align__(16) uint4 vex[2][32][9];  // [buf][pix][cg8+pad] 9,216 B
    __shared__ __align__(16) uint4 swth4[288];     // packed f16x2 weights 4,608 B
    __shared__ int sidx[288];                      // 1,152 B  -> 38,016 B total

    int t    = threadIdx.x;
    int lane = t & 63;
    int wv   = t >> 6;

    int bid = blockIdx.x;           // b*512 + ho*4 + q
    int b   = bid >> 9;
    int r   = bid & 511;
    int ho  = r >> 2;
    int w0  = (r & 3) << 5;

    // ---------------- stage: all 64 ch -> LDS packed f16 octets ------------
    {
        const float* xb = x + (size_t)b * CC * HWW;
#pragma unroll 1
        for (int i = t; i < 8 * 180; i += 256) {
            int cg  = i / 180;
            int pos = i - cg * 180;
            int rr  = pos / 36;
            int cc2 = pos - rr * 36;
            int gy = ho - 2 + rr, gx = w0 - 2 + cc2;
            bool ok = (gy >= 0) & (gy < HH) & (gx >= 0) & (gx < WW);
            int gi = ok ? gy * WW + gx : 0;
            const float* xc = xb + (size_t)cg * 8 * HWW + gi;
            float v0 = xc[0],       v1 = xc[HWW],     v2 = xc[2 * HWW], v3 = xc[3 * HWW];
            float v4 = xc[4 * HWW], v5 = xc[5 * HWW], v6 = xc[6 * HWW], v7 = xc[7 * HWW];
            if (!ok) { v0=0.f; v1=0.f; v2=0.f; v3=0.f; v4=0.f; v5=0.f; v6=0.f; v7=0.f; }
            uint4 p;
            p.x = h2u(__floats2half2_rn(v0, v1));
            p.y = h2u(__floats2half2_rn(v2, v3));
            p.z = h2u(__floats2half2_rn(v4, v5));
            p.w = h2u(__floats2half2_rn(v6, v7));
            Xw[cg * 180 + pos] = p;
        }
    }
    __syncthreads();

    // ---------------- om conv: B = one b128 from window, 2 MFMAs/chunk -----
    f32x4 accom = (f32x4){0.f, 0.f, 0.f, 0.f};
    {
        int og = wv & 1;
        int s  = wv >> 1;
        int pix_s = s * 16 + (lane & 15);
        int oct   = lane >> 4;          // k-octet 0..3 within chunk
#pragma unroll 1
        for (int ch = 0; ch < 18; ch++) {
            int half = ch / 9;
            int tap  = ch - half * 9;
            int ky = tap / 3, kx = tap - ky * 3;
            int pos = (ky + 1) * 36 + pix_s + kx + 1;
            uint4 pw = Xw[(half * 4 + oct) * 180 + pos];
            union { f16x8 v; uint4 u; } B; B.u = pw;
            const f16x8 ah = *(const f16x8*)&womh[((size_t)(ch * 2 + og) * 64 + lane) * 8];
            const f16x8 al = *(const f16x8*)&woml[((size_t)(ch * 2 + og) * 64 + lane) * 8];
            accom = __builtin_amdgcn_mfma_f32_16x16x32_f16(ah, B.v, accom, 0, 0, 0);
            accom = __builtin_amdgcn_mfma_f32_16x16x32_f16(al, B.v, accom, 0, 0, 0);
        }
    }

    // om epilogue -> omL (union with vex region; unused until main loop)
    float* omL = (float*)&vex[0][0][0];   // 27*32 floats = 3,456 B < 9,216 B
    {
        int og = wv & 1, s = wv >> 1;
#pragma unroll
        for (int rg = 0; rg < 4; rg++) {
            int m = og * 16 + (lane >> 4) * 4 + rg;
            if (m < 27) {
                int pp = s * 16 + (lane & 15);
                float v = accom[rg] + om_bias[m];
                if (m >= 18) v = 1.f / (1.f + expf(-v));
                omL[m * 32 + pp] = v;
            }
        }
    }
    __syncthreads();

    // phase B: sampling params per (tap, pixel) -> packed f16x2 weights
#pragma unroll 1
    for (int it = t; it < 288; it += 256) {
        int k  = it >> 5;
        int pp = it & 31;
        float oy = omL[k * 32 + pp];
        float ox = omL[(9 + k) * 32 + pp];
        float mm = omL[(18 + k) * 32 + pp];
        int ky = k / 3, kx = k - ky * 3;
        float py = oy + (float)(ho + ky - 1);
        float px = ox + (float)(w0 + pp + kx - 1);
        float fy = floorf(py), fx = floorf(px);
        float ly = py - fy, lx = px - fx;
        int y0 = (int)fy, x0 = (int)fx;
        bool vy0 = (y0 >= 0) & (y0 < HH);
        bool vy1 = (y0 + 1 >= 0) & (y0 + 1 < HH);
        bool vx0 = (x0 >= 0) & (x0 < WW);
        bool vx1 = (x0 + 1 >= 0) & (x0 + 1 < WW);
        float w00 = (vy0 & vx0) ? (1.f - ly) * (1.f - lx) * mm : 0.f;
        float w01 = (vy0 & vx1) ? (1.f - ly) * lx * mm : 0.f;
        float w10 = (vy1 & vx0) ? ly * (1.f - lx) * mm : 0.f;
        float w11 = (vy1 & vx1) ? ly * lx * mm : 0.f;
        uint4 wp;
        wp.x = h2u(__float2half2_rn(w00));
        wp.y = h2u(__float2half2_rn(w01));
        wp.z = h2u(__float2half2_rn(w10));
        wp.w = h2u(__float2half2_rn(w11));
        swth4[it] = wp;
        bool inw = (y0 >= ho - 2) & (y0 <= ho + 1) & (x0 >= w0 - 2) & (x0 <= w0 + 32);
        int y0c = min(max(y0, -8), 135);
        int x0c = min(max(x0, -8), 135);
        sidx[it] = ((y0c + 16) << 16) | ((x0c + 16) & 0xFFFF)
                 | (inw ? 0 : (int)0x80000000);
    }
    __syncthreads();

    // ---------------- main conv: whole-tap exchange, 8 MFMAs/barrier -------
    f32x4 acc[2];
    acc[0] = (f32x4){0.f, 0.f, 0.f, 0.f};
    acc[1] = (f32x4){0.f, 0.f, 0.f, 0.f};

    {
        int pix = t & 31;
        int cg  = t >> 5;               // 0..7: 8-channel octet over full C=64
#pragma unroll 1
        for (int tap = 0; tap < 9; tap++) {
            int buf  = tap & 1;
            int item = tap * 32 + pix;
            uint4 wp = swth4[item];
            int sv = sidx[item];
            int y0 = ((sv >> 16) & 0x7FFF) - 16;
            int x0 = (sv & 0xFFFF) - 16;
            // A frags: chunk0 = ch tap (half0), chunk1 = ch 9+tap (half1)
            const f16x8 ah0 = *(const f16x8*)&whf[((size_t)(tap * 4 + wv) * 64 + lane) * 8];
            const f16x8 al0 = *(const f16x8*)&wlf[((size_t)(tap * 4 + wv) * 64 + lane) * 8];
            const f16x8 ah1 = *(const f16x8*)&whf[((size_t)((9 + tap) * 4 + wv) * 64 + lane) * 8];
            const f16x8 al1 = *(const f16x8*)&wlf[((size_t)((9 + tap) * 4 + wv) * 64 + lane) * 8];

            uint4 payload;
            if (sv >= 0) {
                int o00 = (y0 - ho + 2) * 36 + (x0 - w0 + 2);
                const uint4* Xrow = &Xw[cg * 180];
                uint4 c00 = Xrow[o00];
                uint4 c01 = Xrow[o00 + 1];
                uint4 c10 = Xrow[o00 + 36];
                uint4 c11 = Xrow[o00 + 37];
                __half2 w00 = u2h(wp.x), w01 = u2h(wp.y);
                __half2 w10 = u2h(wp.z), w11 = u2h(wp.w);
                __half2 vA = __hmul2(w00, u2h(c00.x));
                vA = __hfma2(w01, u2h(c01.x), vA);
                vA = __hfma2(w10, u2h(c10.x), vA);
                vA = __hfma2(w11, u2h(c11.x), vA);
                __half2 vB = __hmul2(w00, u2h(c00.y));
                vB = __hfma2(w01, u2h(c01.y), vB);
                vB = __hfma2(w10, u2h(c10.y), vB);
                vB = __hfma2(w11, u2h(c11.y), vB);
                __half2 vC = __hmul2(w00, u2h(c00.z));
                vC = __hfma2(w01, u2h(c01.z), vC);
                vC = __hfma2(w10, u2h(c10.z), vC);
                vC = __hfma2(w11, u2h(c11.z), vC);
                __half2 vD = __hmul2(w00, u2h(c00.w));
                vD = __hfma2(w01, u2h(c01.w), vD);
                vD = __hfma2(w10, u2h(c10.w), vD);
                vD = __hfma2(w11, u2h(c11.w), vD);
                payload.x = h2u(vA); payload.y = h2u(vB);
                payload.z = h2u(vC); payload.w = h2u(vD);
            } else {
                // rare escape: clamped global gather in f32 (8 channels)
                const float* xg = x + ((size_t)(b * CC + cg * 8)) * HWW;
                float w00f = __low2float(u2h(wp.x)), w01f = __low2float(u2h(wp.y));
                float w10f = __low2float(u2h(wp.z)), w11f = __low2float(u2h(wp.w));
                int cy0 = min(max(y0, 0), HH - 1), cy1 = min(max(y0 + 1, 0), HH - 1);
                int cx0 = min(max(x0, 0), WW - 1), cx1 = min(max(x0 + 1, 0), WW - 1);
                int i00 = cy0 * WW + cx0, i01 = cy0 * WW + cx1;
                int i10 = cy1 * WW + cx0, i11 = cy1 * WW + cx1;
                float vv[8];
#pragma unroll
                for (int j = 0; j < 8; j++) {
                    const float* xc = xg + (size_t)j * HWW;
                    vv[j] = w00f * xc[i00] + w01f * xc[i01]
                          + w10f * xc[i10] + w11f * xc[i11];
                }
                payload.x = h2u(__floats2half2_rn(vv[0], vv[1]));
                payload.y = h2u(__floats2half2_rn(vv[2], vv[3]));
                payload.z = h2u(__floats2half2_rn(vv[4], vv[5]));
                payload.w = h2u(__floats2half2_rn(vv[6], vv[7]));
            }
            vex[buf][pix][cg] = payload;
            __syncthreads();
#pragma unroll
            for (int s2 = 0; s2 < 2; s2++) {
                union { f16x8 v; uint4 u; } B0, B1;
                B0.u = vex[buf][s2 * 16 + (lane & 15)][lane >> 4];       // chunk0: cg 0..3
                B1.u = vex[buf][s2 * 16 + (lane & 15)][4 + (lane >> 4)]; // chunk1: cg 4..7
                acc[s2] = __builtin_amdgcn_mfma_f32_16x16x32_f16(ah0, B0.v, acc[s2], 0, 0, 0);
                acc[s2] = __builtin_amdgcn_mfma_f32_16x16x32_f16(al0, B0.v, acc[s2], 0, 0, 0);
                acc[s2] = __builtin_amdgcn_mfma_f32_16x16x32_f16(ah1, B1.v, acc[s2], 0, 0, 0);
                acc[s2] = __builtin_amdgcn_mfma_f32_16x16x32_f16(al1, B1.v, acc[s2], 0, 0, 0);
            }
        }
    }

    // epilogue
    int prow = ho * WW + w0;
#pragma unroll
    for (int s = 0; s < 2; s++) {
#pragma unroll
        for (int rg = 0; rg < 4; rg++) {
            int o  = wv * 16 + (lane >> 4) * 4 + rg;
            int pp = s * 16 + (lane & 15);
            out[((size_t)(b * OO + o)) * HWW + prow + pp] = acc[s][rg] + bias[o];
        }
    }
}

// ---------------------------------------------------------------------------
extern "C" void kernel_launch(void* const* d_in, const int* in_sizes, int n_in,
                              void* d_out, int out_size, void* d_ws, size_t ws_size,
                              hipStream_t stream)
{
    (void)in_sizes; (void)n_in; (void)out_size; (void)ws_size;
    const float* x      = (const float*)d_in[0];
    const float* weight = (const float*)d_in[1];
    const float* bias   = (const float*)d_in[2];
    const float* om_w   = (const float*)d_in[3];
    const float* om_b   = (const float*)d_in[4];
    float* out = (float*)d_out;
    char*  ws  = (char*)d_ws;

    unsigned short* whf  = (unsigned short*)(ws + WHF_OFF);
    unsigned short* wlf  = (unsigned short*)(ws + WLF_OFF);
    unsigned short* womh = (unsigned short*)(ws + WOMH_OFF);
    unsigned short* woml = (unsigned short*)(ws + WOML_OFF);

    int prep_n = 18 * 4 * 64 * 8 + 18 * 2 * 64 * 8;  // 55296
    prep_kernel<<<(prep_n + 255) / 256, 256, 0, stream>>>(weight, om_w, whf, wlf, womh, woml);

    int nblk = BB * HH * (WW / 32);  // 2048
    fused_kernel<<<nblk, 256, 0, stream>>>(x, whf, wlf, womh, woml, bias, om_b, out);
}